// Round 2
// baseline (373.976 us; speedup 1.0000x reference)
//
#include <hip/hip_runtime.h>
#include <hip/hip_cooperative_groups.h>
#include <stdint.h>

namespace cg = cooperative_groups;

#define B 128
#define F 8192
#define H 8192
#define S 4
#define K 32
#define L 3
#define C 100

// ---------------------------------------------------------------------------
// Planar-PAIR activation layout: PP[wp][h] = uint2{ word(2wp), word(2wp+1) },
// wp in {0,1}; word w covers batches w*32..w*32+31, bit = b & 31.
// As u32 array: index (wp*H + h)*2 + comp.
// ---------------------------------------------------------------------------

__device__ __forceinline__ int load_threshold(const int* p) {
    int v = *p;
    if (v >= (1 << 23)) v = (int)__int_as_float(v);
    return v;
}

// carry-save add of one 0/1-mask word into a 5-deep bit-sliced counter
__device__ __forceinline__ void cs5(uint32_t* a, uint32_t v) {
#pragma unroll
    for (int i = 0; i < 5; ++i) { const uint32_t t = a[i]; a[i] = t ^ v; v = t & v; }
}

// sum own 5-bit sliced counter with lane^32 partner's -> 6-bit result in y
__device__ __forceinline__ void pair_sum5(const uint32_t* x, uint32_t* y) {
    uint32_t c = 0;
#pragma unroll
    for (int i = 0; i < 5; ++i) {
        const uint32_t p = (uint32_t)__shfl_xor((int)x[i], 32);
        const uint32_t s = x[i] ^ p;
        y[i] = s ^ c;
        c = (x[i] & p) | (s & c);
    }
    y[5] = c;
}

// fired = (2P >= A + thr), bit-sliced over 7 bits; A,P are 6-deep (<=32)
__device__ __forceinline__ uint32_t fired_cmp(const uint32_t* A, const uint32_t* P, int thr) {
    uint32_t Y[7];
    uint32_t c = 0;
#pragma unroll
    for (int i = 0; i < 7; ++i) {
        const uint32_t ai = (i < 6) ? A[i] : 0u;
        const uint32_t bm = ((thr >> i) & 1) ? 0xFFFFFFFFu : 0u;
        const uint32_t t  = ai ^ bm;
        Y[i] = t ^ c;
        c = (ai & bm) | (t & c);
    }
    uint32_t bw = 0;
#pragma unroll
    for (int i = 0; i < 7; ++i) {
        const uint32_t xx = (i >= 1) ? P[i - 1] : 0u;
        const uint32_t d  = xx ^ Y[i];
        bw = ((~xx) & Y[i]) | ((~d) & bw);
    }
    return ~bw;
}

// async global->LDS, 16 B per lane
#define GLDS16(gp, lp)                                                \
    __builtin_amdgcn_global_load_lds(                                 \
        (const __attribute__((address_space(1))) uint32_t*)(gp),      \
        (__attribute__((address_space(3))) uint32_t*)(lp), 16, 0, 0)

#define HG 32
#define ISTRIDE 35

// ---------------------------------------------------------------------------
// One layer: block = 32 h-rows x ALL 4 words x ALL 4 segments (512 threads,
// hg = blockIdx). tab[2][H] uint2 staged via global_load_lds dwordx4;
// isg (idx|signbit) staged once, stride-35 rows (conflict-free b32 reads).
// Wave ww: s=ww&3, wp=ww>>2; lane: h5=lane&31, kh=lane>>5 (K split 16/16,
// combined via shfl_xor(32)); uint2 gather feeds carry-save counters for
// BOTH words of the pair; bit-sliced compare; OR across segments via LDS.
// ---------------------------------------------------------------------------
__device__ __forceinline__ void layer_phase(
        const uint32_t* __restrict__ prevPP,   // [2][H] uint2, as u32*
        const int* __restrict__ idx,           // (S,H,K)
        const float* __restrict__ signs,       // (S,H,K)
        uint32_t* __restrict__ outPP,          // [2][H] uint2, as u32*
        const int thr, const int hg, const int tid,
        uint2* tab, uint32_t* isg, uint32_t* fbuf) {
    // ---- stage tab: 128 KiB contiguous, async direct-to-LDS ----
    {
        uint32_t* lbase = (uint32_t*)tab;
#pragma unroll
        for (int i = 0; i < 16; ++i) {
            const int o = (i * 512 + tid) * 4;      // u32 index, 16B/lane
            GLDS16(prevPP + o, lbase + o);
        }
    }
    // ---- stage isg once: thread t packs 8 entries (coalesced 32B reads) ----
    {
        const int s    = tid >> 7;                  // 0..3
        const int hrow = (tid & 127) >> 2;          // 0..31
        const int k0   = (tid & 3) * 8;             // 0,8,16,24
        const size_t gb = ((size_t)s * H + (size_t)hg * HG + hrow) * K + k0;
        const int4   ia = *(const int4*)(idx + gb);
        const int4   ic = *(const int4*)(idx + gb + 4);
        const float4 sa = *(const float4*)(signs + gb);
        const float4 sc = *(const float4*)(signs + gb + 4);
        uint32_t* dst = &isg[(s * HG + hrow) * ISTRIDE + k0];
        dst[0] = (uint32_t)ia.x | ((uint32_t)__float_as_int(sa.x) & 0x80000000u);
        dst[1] = (uint32_t)ia.y | ((uint32_t)__float_as_int(sa.y) & 0x80000000u);
        dst[2] = (uint32_t)ia.z | ((uint32_t)__float_as_int(sa.z) & 0x80000000u);
        dst[3] = (uint32_t)ia.w | ((uint32_t)__float_as_int(sa.w) & 0x80000000u);
        dst[4] = (uint32_t)ic.x | ((uint32_t)__float_as_int(sc.x) & 0x80000000u);
        dst[5] = (uint32_t)ic.y | ((uint32_t)__float_as_int(sc.y) & 0x80000000u);
        dst[6] = (uint32_t)ic.z | ((uint32_t)__float_as_int(sc.z) & 0x80000000u);
        dst[7] = (uint32_t)ic.w | ((uint32_t)__float_as_int(sc.w) & 0x80000000u);
    }
    __syncthreads();   // drains vmcnt (global_load_lds) + lgkmcnt (ds_writes)

    // ---- gather + bit-sliced accumulate (2 words per gather) ----
    const int lane = tid & 63;
    const int ww   = tid >> 6;        // 0..7
    const int s    = ww & 3;
    const int wp   = ww >> 2;
    const int kh   = lane >> 5;       // k half: 0 -> k0..15, 1 -> k16..31
    const int h5   = lane & 31;

    uint32_t A0[5] = {0,0,0,0,0}, P0[5] = {0,0,0,0,0};
    uint32_t A1[5] = {0,0,0,0,0}, P1[5] = {0,0,0,0,0};
    const uint32_t* row = &isg[(s * HG + h5) * ISTRIDE + kh * 16];
    const uint2*    tw  = &tab[wp * H];
#pragma unroll
    for (int c8 = 0; c8 < 2; ++c8) {
        uint32_t iv[8];
#pragma unroll
        for (int j = 0; j < 8; ++j) iv[j] = row[c8 * 8 + j];
        uint2 g[8];
#pragma unroll
        for (int j = 0; j < 8; ++j) g[j] = tw[iv[j] & 0xFFFFu];
#pragma unroll
        for (int j = 0; j < 8; ++j) {
            const uint32_t pm = ~(uint32_t)((int32_t)iv[j] >> 31);  // ~0 if +
            cs5(A0, g[j].x);
            cs5(P0, g[j].x & pm);
            cs5(A1, g[j].y);
            cs5(P1, g[j].y & pm);
        }
    }

    // ---- combine k halves (lane^32) -> 6-bit counters ----
    uint32_t A0f[6], P0f[6], A1f[6], P1f[6];
    pair_sum5(A0, A0f);
    pair_sum5(P0, P0f);
    pair_sum5(A1, A1f);
    pair_sum5(P1, P1f);

    const uint32_t f0 = fired_cmp(A0f, P0f, thr);   // word 2wp
    const uint32_t f1 = fired_cmp(A1f, P1f, thr);   // word 2wp+1

    if (kh == 0) {
        fbuf[(ww * HG + h5) * 2 + 0] = f0;
        fbuf[(ww * HG + h5) * 2 + 1] = f1;
    }
    __syncthreads();

    // ---- OR across 4 segments, write 128 u32 (coalesced) ----
    if (tid < 128) {
        const int wp2  = tid >> 6;
        const int comp = (tid >> 5) & 1;
        const int hh   = tid & 31;
        uint32_t v = 0;
#pragma unroll
        for (int s2 = 0; s2 < 4; ++s2)
            v |= fbuf[((wp2 * 4 + s2) * HG + hh) * 2 + comp];
        outPP[((size_t)wp2 * H + (size_t)hg * HG + hh) * 2 + comp] = v;
    }
}

// ---------------------------------------------------------------------------
// FUSED persistent cooperative kernel: 256 blocks x 512 threads, 1 block/CU.
// P0 pack+zero | P1..P3 layers | P4 final, grid.sync() between phases.
// ---------------------------------------------------------------------------
__global__ __launch_bounds__(512, 2) void fused_kernel(
        const float* __restrict__ x,
        const int* __restrict__ idx0, const float* __restrict__ signs0,
        const int* __restrict__ idxH, const float* __restrict__ signsH,
        const float* __restrict__ wout, const int* __restrict__ thrp,
        uint2* __restrict__ xPP, uint32_t* __restrict__ actPP,
        float* __restrict__ out) {
    __shared__ uint2    tab[2 * H];                  // 128 KiB
    __shared__ uint32_t isg[S * HG * ISTRIDE];       // 17.5 KiB
    __shared__ uint32_t fbuf[8 * HG * 2];            // 2 KiB

    cg::grid_group grid = cg::this_grid();
    const int tid = threadIdx.x;
    const int bid = blockIdx.x;
    const int thr = load_threshold(thrp);

    // ---- P0: zero out + pack x (32 f-columns per block, all 512 threads) ----
    {
        const int zi = bid * 512 + tid;
        if (zi < B * C) out[zi] = 0.0f;

        const int b   = tid & 127;
        const int wv  = (tid >> 6) & 1;       // word pair
        const int sub = tid >> 7;             // 0..3 -> j = 2*sub..2*sub+1
        const int f0  = bid * 32;
        const float4* xr = (const float4*)(x + (size_t)b * F + f0);
#pragma unroll
        for (int jj = 0; jj < 2; ++jj) {
            const int j = sub * 2 + jj;
            const float4 v = xr[j];
            const uint64_t m0 = __ballot(v.x > 0.5f);
            const uint64_t m1 = __ballot(v.y > 0.5f);
            const uint64_t m2 = __ballot(v.z > 0.5f);
            const uint64_t m3 = __ballot(v.w > 0.5f);
            if ((tid & 63) == 0) {
                const int f = f0 + 4 * j;
                uint4* dst = (uint4*)(xPP + (size_t)wv * F + f);
                dst[0] = make_uint4((uint32_t)m0, (uint32_t)(m0 >> 32),
                                    (uint32_t)m1, (uint32_t)(m1 >> 32));
                dst[1] = make_uint4((uint32_t)m2, (uint32_t)(m2 >> 32),
                                    (uint32_t)m3, (uint32_t)(m3 >> 32));
            }
        }
    }
    __threadfence();
    grid.sync();

    // ---- P1..P3: layers ----
    layer_phase((const uint32_t*)xPP, idx0, signs0, actPP,
                thr, bid, tid, tab, isg, fbuf);
    __threadfence();
    grid.sync();

    layer_phase(actPP, idxH, signsH, actPP + (size_t)4 * H,
                thr, bid, tid, tab, isg, fbuf);
    __threadfence();
    grid.sync();

    layer_phase(actPP + (size_t)4 * H, idxH + (size_t)S * H * K,
                signsH + (size_t)S * H * K, actPP + (size_t)8 * H,
                thr, bid, tid, tab, isg, fbuf);
    __threadfence();
    grid.sync();

    // ---- P4: final. 2048 waves = 128 b x 16 h-chunks (512 h each) ----
    {
        const int lane = tid & 63;
        const int gw   = bid * 8 + (tid >> 6);
        const int b    = gw >> 4;
        const int hc   = gw & 15;
        const int w32  = b >> 5;
        const int wp   = w32 >> 1;
        const int comp = w32 & 1;
        const int bit  = b & 31;

        float acc0 = 0.0f, acc1 = 0.0f;
        const int c1 = 64 + lane;
        const bool c1v = (c1 < C);

        for (int l = 0; l < L; ++l) {
            const uint32_t* aT = actPP + ((size_t)(l * 2 + wp) * H) * 2 + comp;
            const float* wl = wout + (size_t)l * H * C;
            for (int r = 0; r < 8; ++r) {
                const int hbase = hc * 512 + r * 64;
                const uint32_t m = aT[(size_t)(hbase + lane) * 2];
                uint64_t hm = __ballot((m >> bit) & 1u);
                while (hm) {
                    const int slot = __ffsll((unsigned long long)hm) - 1;
                    hm &= hm - 1;
                    const float* wr = wl + (size_t)(hbase + slot) * C;
                    acc0 += wr[lane];
                    if (c1v) acc1 += wr[c1];
                }
            }
        }
        atomicAdd(&out[b * C + lane], acc0);
        if (c1v) atomicAdd(&out[b * C + c1], acc1);
    }
}

// ---------------------------------------------------------------------------
// Fallback path (5 separate kernels) in case cooperative launch is rejected
// under graph capture. Bodies identical to the fused phases.
// ---------------------------------------------------------------------------
__global__ void pack_x_kernel(const float* __restrict__ x, uint2* __restrict__ xPP,
                              float* __restrict__ out) {
    const int zi = blockIdx.x * 128 + threadIdx.x;
    if (zi < B * C) out[zi] = 0.0f;

    const int b  = threadIdx.x;
    const int wv = threadIdx.x >> 6;
    const int f0 = blockIdx.x * 32;
    const float4* xr = (const float4*)(x + (size_t)b * F + f0);
    for (int j = 0; j < 8; ++j) {
        const float4 v = xr[j];
        const uint64_t m0 = __ballot(v.x > 0.5f);
        const uint64_t m1 = __ballot(v.y > 0.5f);
        const uint64_t m2 = __ballot(v.z > 0.5f);
        const uint64_t m3 = __ballot(v.w > 0.5f);
        if ((threadIdx.x & 63) == 0) {
            const int f = f0 + 4 * j;
            uint4* dst = (uint4*)(xPP + (size_t)wv * F + f);
            dst[0] = make_uint4((uint32_t)m0, (uint32_t)(m0 >> 32),
                                (uint32_t)m1, (uint32_t)(m1 >> 32));
            dst[1] = make_uint4((uint32_t)m2, (uint32_t)(m2 >> 32),
                                (uint32_t)m3, (uint32_t)(m3 >> 32));
        }
    }
}

__global__ __launch_bounds__(512, 2) void layer_kernel(
        const uint32_t* __restrict__ prevPP, const int* __restrict__ idx,
        const float* __restrict__ signs, uint32_t* __restrict__ outPP,
        const int* __restrict__ thrp) {
    __shared__ uint2    tab[2 * H];
    __shared__ uint32_t isg[S * HG * ISTRIDE];
    __shared__ uint32_t fbuf[8 * HG * 2];
    layer_phase(prevPP, idx, signs, outPP, load_threshold(thrp),
                blockIdx.x, threadIdx.x, tab, isg, fbuf);
}

#define NHC 32
#define HCH (H / NHC)

__global__ void final_kernel(const uint32_t* __restrict__ actU,
                             const float* __restrict__ wout,
                             float* __restrict__ out) {
    const int lane = threadIdx.x & 63;
    const int wid  = threadIdx.x >> 6;
    const int hc   = blockIdx.x & (NHC - 1);
    const int bg   = blockIdx.x / NHC;
    const int b    = bg * 4 + wid;
    const int w32  = b >> 5;
    const int wp   = w32 >> 1;
    const int comp = w32 & 1;
    const int bit  = b & 31;

    float acc0 = 0.0f, acc1 = 0.0f;
    const int c1 = 64 + lane;
    const bool c1v = (c1 < C);

    for (int l = 0; l < L; ++l) {
        const uint32_t* aT = actU + ((size_t)(l * 2 + wp) * H) * 2 + comp;
        const float* wl = wout + (size_t)l * H * C;
        for (int r = 0; r < HCH / 64; ++r) {
            const int hbase = hc * HCH + r * 64;
            const uint32_t m = aT[(size_t)(hbase + lane) * 2];
            uint64_t hm = __ballot((m >> bit) & 1u);
            while (hm) {
                const int slot = __ffsll((unsigned long long)hm) - 1;
                hm &= hm - 1;
                const float* wr = wl + (size_t)(hbase + slot) * C;
                acc0 += wr[lane];
                if (c1v) acc1 += wr[c1];
            }
        }
    }
    atomicAdd(&out[b * C + lane], acc0);
    if (c1v) atomicAdd(&out[b * C + c1], acc1);
}

// ---------------------------------------------------------------------------
extern "C" void kernel_launch(void* const* d_in, const int* in_sizes, int n_in,
                              void* d_out, int out_size, void* d_ws, size_t ws_size,
                              hipStream_t stream) {
    const float* x      = (const float*)d_in[0];   // (B,F)
    const float* signs0 = (const float*)d_in[1];   // (S,H,K)
    const float* signsH = (const float*)d_in[2];   // (L-1,S,H,K)
    const float* wout   = (const float*)d_in[3];   // (L,H,C)
    const int*   idx0   = (const int*)d_in[4];     // (S,H,K)
    const int*   idxH   = (const int*)d_in[5];     // (L-1,S,H,K)
    const int*   thr    = (const int*)d_in[6];     // scalar
    float* out = (float*)d_out;                    // (B,C)

    // Workspace: xPP [2][F] uint2 (128 KiB), actPP [L][2][H] uint2 (384 KiB)
    uint32_t* xPP   = (uint32_t*)d_ws;
    uint32_t* actPP = xPP + (size_t)4 * F;
    uint2*    xPP2  = (uint2*)d_ws;

    void* args[] = { (void*)&x, (void*)&idx0, (void*)&signs0,
                     (void*)&idxH, (void*)&signsH, (void*)&wout, (void*)&thr,
                     (void*)&xPP2, (void*)&actPP, (void*)&out };
    hipError_t e = hipLaunchCooperativeKernel((const void*)fused_kernel,
                                              dim3(256), dim3(512),
                                              args, 0, stream);
    if (e != hipSuccess) {
        (void)hipGetLastError();   // clear, fall back to 5-dispatch path
        pack_x_kernel<<<F / 32, 128, 0, stream>>>(x, xPP2, out);
        layer_kernel<<<H / HG, 512, 0, stream>>>(xPP, idx0, signs0, actPP, thr);
        layer_kernel<<<H / HG, 512, 0, stream>>>(actPP, idxH, signsH,
                                                 actPP + (size_t)4 * H, thr);
        layer_kernel<<<H / HG, 512, 0, stream>>>(actPP + (size_t)4 * H,
                                                 idxH + (size_t)S * H * K,
                                                 signsH + (size_t)S * H * K,
                                                 actPP + (size_t)8 * H, thr);
        final_kernel<<<32 * NHC, 256, 0, stream>>>(actPP, wout, out);
    }
}

// Round 3
// 165.512 us; speedup vs baseline: 2.2595x; 2.2595x over previous
//
#include <hip/hip_runtime.h>
#include <stdint.h>

#define B 128
#define F 8192
#define H 8192
#define S 4
#define K 32
#define L 3
#define C 100

#define HG 32
#define ISTRIDE 35
#define NBLK 256
#define NTHR 512

// ---------------------------------------------------------------------------
// Planar-PAIR activation layout: PP[wp][h] = uint2{ word(2wp), word(2wp+1) },
// wp in {0,1}; word w covers batches w*32..w*32+31, bit = b & 31.
// As u32 array: index (wp*H + h)*2 + comp.
// ---------------------------------------------------------------------------

__device__ __forceinline__ int load_threshold(const int* p) {
    int v = *p;
    if (v >= (1 << 23)) v = (int)__int_as_float(v);
    return v;
}

// carry-save add of one 0/1-mask word into a 5-deep bit-sliced counter
__device__ __forceinline__ void cs5(uint32_t* a, uint32_t v) {
#pragma unroll
    for (int i = 0; i < 5; ++i) { const uint32_t t = a[i]; a[i] = t ^ v; v = t & v; }
}

// sum own 5-bit sliced counter with lane^32 partner's -> 6-bit result in y
__device__ __forceinline__ void pair_sum5(const uint32_t* x, uint32_t* y) {
    uint32_t c = 0;
#pragma unroll
    for (int i = 0; i < 5; ++i) {
        const uint32_t p = (uint32_t)__shfl_xor((int)x[i], 32);
        const uint32_t s = x[i] ^ p;
        y[i] = s ^ c;
        c = (x[i] & p) | (s & c);
    }
    y[5] = c;
}

// fired = (2P >= A + thr), bit-sliced over 7 bits; A,P are 6-deep (<=32)
__device__ __forceinline__ uint32_t fired_cmp(const uint32_t* A, const uint32_t* P, int thr) {
    uint32_t Y[7];
    uint32_t c = 0;
#pragma unroll
    for (int i = 0; i < 7; ++i) {
        const uint32_t ai = (i < 6) ? A[i] : 0u;
        const uint32_t bm = ((thr >> i) & 1) ? 0xFFFFFFFFu : 0u;
        const uint32_t t  = ai ^ bm;
        Y[i] = t ^ c;
        c = (ai & bm) | (t & c);
    }
    uint32_t bw = 0;
#pragma unroll
    for (int i = 0; i < 7; ++i) {
        const uint32_t xx = (i >= 1) ? P[i - 1] : 0u;
        const uint32_t d  = xx ^ Y[i];
        bw = ((~xx) & Y[i]) | ((~d) & bw);
    }
    return ~bw;
}

// async global->LDS, 16 B per lane
#define GLDS16(gp, lp)                                                \
    __builtin_amdgcn_global_load_lds(                                 \
        (const __attribute__((address_space(1))) uint32_t*)(gp),      \
        (__attribute__((address_space(3))) uint32_t*)(lp), 16, 0, 0)

#define AG_LOAD(p)                                                          \
    __hip_atomic_load((p), __ATOMIC_RELAXED, __HIP_MEMORY_SCOPE_AGENT)
#define AG_STORE(p, v)                                                      \
    __hip_atomic_store((p), (v), __ATOMIC_RELAXED, __HIP_MEMORY_SCOPE_AGENT)

// ---------------------------------------------------------------------------
// Pure-atomic grid barrier: NO device-scope fences (no buffer_inv/wbl2).
// Payload coherence is handled by agent-scope (sc1, LLC-level) atomics on
// the payload itself. cnt = bar[0], flag = bar[32] (separate cache lines).
// ---------------------------------------------------------------------------
__device__ __forceinline__ void grid_barrier(uint32_t* bar, uint32_t target, int tid) {
    asm volatile("s_waitcnt vmcnt(0)" ::: "memory");   // payload stores at LLC
    __syncthreads();
    if (tid == 0) {
        const uint32_t t = __hip_atomic_fetch_add(&bar[0], 1u, __ATOMIC_RELAXED,
                                                  __HIP_MEMORY_SCOPE_AGENT) + 1u;
        if (t == target * NBLK) AG_STORE(&bar[32], target);
        int guard = 0;
        while (AG_LOAD(&bar[32]) < target) {
            __builtin_amdgcn_s_sleep(2);
            if (++guard > (1 << 20)) break;            // fail loud, don't hang
        }
    }
    __syncthreads();
    asm volatile("" ::: "memory");
}

// ---------------------------------------------------------------------------
// One layer: block = 32 h-rows x ALL 4 words x ALL 4 segments (512 threads,
// hg = blockIdx). tab[2][H] uint2 staged from prevPP; isg (idx|signbit)
// staged once, stride-35 rows. Wave ww: s=ww&3, wp=ww>>2; lane: h5=lane&31,
// kh=lane>>5 (K split 16/16, combined via shfl_xor(32)); uint2 gathers feed
// carry-save counters for BOTH words of the pair; bit-sliced compare;
// OR across segments via LDS.
// AGL: stage tab via agent-scope atomic u64 loads (intra-kernel producer on
//      another XCD) instead of global_load_lds.
// AGS: store outPP via agent-scope atomics (consumed intra-kernel).
// ---------------------------------------------------------------------------
template<bool AGL, bool AGS>
__device__ __forceinline__ void layer_phase(
        const uint32_t* __restrict__ prevPP,   // [2][H] uint2, as u32*
        const int* __restrict__ idx,           // (S,H,K)
        const float* __restrict__ signs,       // (S,H,K)
        uint32_t* __restrict__ outPP,          // [2][H] uint2, as u32*
        const int thr, const int hg, const int tid,
        uint2* tab, uint32_t* isg, uint32_t* fbuf) {
    // ---- stage tab: 128 KiB contiguous ----
    if (!AGL) {
        uint32_t* lbase = (uint32_t*)tab;
#pragma unroll
        for (int i = 0; i < 16; ++i) {
            const int o = (i * 512 + tid) * 4;      // u32 index, 16B/lane
            GLDS16(prevPP + o, lbase + o);
        }
    } else {
        const unsigned long long* src = (const unsigned long long*)prevPP;
        unsigned long long* dst = (unsigned long long*)tab;
#pragma unroll
        for (int c = 0; c < 4; ++c) {
            unsigned long long v[8];
#pragma unroll
            for (int i = 0; i < 8; ++i)
                v[i] = AG_LOAD(src + (size_t)(c * 8 + i) * 512 + tid);
#pragma unroll
            for (int i = 0; i < 8; ++i)
                dst[(size_t)(c * 8 + i) * 512 + tid] = v[i];
        }
    }
    // ---- stage isg once: thread t packs 8 entries (coalesced 32B reads) ----
    {
        const int s    = tid >> 7;                  // 0..3
        const int hrow = (tid & 127) >> 2;          // 0..31
        const int k0   = (tid & 3) * 8;             // 0,8,16,24
        const size_t gb = ((size_t)s * H + (size_t)hg * HG + hrow) * K + k0;
        const int4   ia = *(const int4*)(idx + gb);
        const int4   ic = *(const int4*)(idx + gb + 4);
        const float4 sa = *(const float4*)(signs + gb);
        const float4 sc = *(const float4*)(signs + gb + 4);
        uint32_t* dst = &isg[(s * HG + hrow) * ISTRIDE + k0];
        dst[0] = (uint32_t)ia.x | ((uint32_t)__float_as_int(sa.x) & 0x80000000u);
        dst[1] = (uint32_t)ia.y | ((uint32_t)__float_as_int(sa.y) & 0x80000000u);
        dst[2] = (uint32_t)ia.z | ((uint32_t)__float_as_int(sa.z) & 0x80000000u);
        dst[3] = (uint32_t)ia.w | ((uint32_t)__float_as_int(sa.w) & 0x80000000u);
        dst[4] = (uint32_t)ic.x | ((uint32_t)__float_as_int(sc.x) & 0x80000000u);
        dst[5] = (uint32_t)ic.y | ((uint32_t)__float_as_int(sc.y) & 0x80000000u);
        dst[6] = (uint32_t)ic.z | ((uint32_t)__float_as_int(sc.z) & 0x80000000u);
        dst[7] = (uint32_t)ic.w | ((uint32_t)__float_as_int(sc.w) & 0x80000000u);
    }
    __syncthreads();   // drains vmcnt (global_load_lds) + lgkmcnt (ds_writes)

    // ---- gather + bit-sliced accumulate (2 words per gather) ----
    const int lane = tid & 63;
    const int ww   = tid >> 6;        // 0..7
    const int s    = ww & 3;
    const int wp   = ww >> 2;
    const int kh   = lane >> 5;       // k half: 0 -> k0..15, 1 -> k16..31
    const int h5   = lane & 31;

    uint32_t A0[5] = {0,0,0,0,0}, P0[5] = {0,0,0,0,0};
    uint32_t A1[5] = {0,0,0,0,0}, P1[5] = {0,0,0,0,0};
    const uint32_t* row = &isg[(s * HG + h5) * ISTRIDE + kh * 16];
    const uint2*    tw  = &tab[wp * H];
#pragma unroll
    for (int c8 = 0; c8 < 2; ++c8) {
        uint32_t iv[8];
#pragma unroll
        for (int j = 0; j < 8; ++j) iv[j] = row[c8 * 8 + j];
        uint2 g[8];
#pragma unroll
        for (int j = 0; j < 8; ++j) g[j] = tw[iv[j] & 0xFFFFu];
#pragma unroll
        for (int j = 0; j < 8; ++j) {
            const uint32_t pm = ~(uint32_t)((int32_t)iv[j] >> 31);  // ~0 if +
            cs5(A0, g[j].x);
            cs5(P0, g[j].x & pm);
            cs5(A1, g[j].y);
            cs5(P1, g[j].y & pm);
        }
    }

    // ---- combine k halves (lane^32) -> 6-bit counters ----
    uint32_t A0f[6], P0f[6], A1f[6], P1f[6];
    pair_sum5(A0, A0f);
    pair_sum5(P0, P0f);
    pair_sum5(A1, A1f);
    pair_sum5(P1, P1f);

    const uint32_t f0 = fired_cmp(A0f, P0f, thr);   // word 2wp
    const uint32_t f1 = fired_cmp(A1f, P1f, thr);   // word 2wp+1

    if (kh == 0) {
        fbuf[(ww * HG + h5) * 2 + 0] = f0;
        fbuf[(ww * HG + h5) * 2 + 1] = f1;
    }
    __syncthreads();

    // ---- OR across 4 segments, write 128 u32 (coalesced) ----
    if (tid < 128) {
        const int wp2  = tid >> 6;
        const int comp = (tid >> 5) & 1;
        const int hh   = tid & 31;
        uint32_t v = 0;
#pragma unroll
        for (int s2 = 0; s2 < 4; ++s2)
            v |= fbuf[((wp2 * 4 + s2) * HG + hh) * 2 + comp];
        uint32_t* op = &outPP[((size_t)wp2 * H + (size_t)hg * HG + hh) * 2 + comp];
        if (AGS) AG_STORE(op, v); else *op = v;
    }
}

// ---------------------------------------------------------------------------
// Init kernel (normal dispatch): zero out + barrier state, pack x -> xPP.
// 256 blocks x 128 threads (thread = b), 32 f per block.
// Dispatch-boundary coherence makes xPP visible to the coop kernel's
// global_load_lds staging (no atomics needed for layer-1 input).
// ---------------------------------------------------------------------------
__global__ __launch_bounds__(128) void init_pack_kernel(
        const float* __restrict__ x, uint2* __restrict__ xPP,
        float* __restrict__ out, uint32_t* __restrict__ bar) {
    const int zi = blockIdx.x * 128 + threadIdx.x;
    if (zi < B * C) out[zi] = 0.0f;
    if (zi == 0) { bar[0] = 0u; bar[32] = 0u; }

    const int b  = threadIdx.x;          // 0..127
    const int wv = threadIdx.x >> 6;     // word pair (0,1)
    const int f0 = blockIdx.x * 32;
    const float4* xr = (const float4*)(x + (size_t)b * F + f0);
    for (int j = 0; j < 8; ++j) {
        const float4 v = xr[j];
        const uint64_t m0 = __ballot(v.x > 0.5f);
        const uint64_t m1 = __ballot(v.y > 0.5f);
        const uint64_t m2 = __ballot(v.z > 0.5f);
        const uint64_t m3 = __ballot(v.w > 0.5f);
        if ((threadIdx.x & 63) == 0) {
            const int f = f0 + 4 * j;
            uint4* dst = (uint4*)(xPP + (size_t)wv * F + f);
            dst[0] = make_uint4((uint32_t)m0, (uint32_t)(m0 >> 32),
                                (uint32_t)m1, (uint32_t)(m1 >> 32));
            dst[1] = make_uint4((uint32_t)m2, (uint32_t)(m2 >> 32),
                                (uint32_t)m3, (uint32_t)(m3 >> 32));
        }
    }
}

// ---------------------------------------------------------------------------
// FUSED persistent cooperative kernel: 256 blocks x 512 threads, 1 block/CU.
// L1 | bar | L2 | bar | L3 | bar | final. Pure-atomic barriers; all
// intra-kernel cross-block payload via agent-scope atomics (sc1 @ LLC).
// ---------------------------------------------------------------------------
__global__ __launch_bounds__(512, 2) void fused_kernel(
        const uint32_t* __restrict__ xPP,
        const int* __restrict__ idx0, const float* __restrict__ signs0,
        const int* __restrict__ idxH, const float* __restrict__ signsH,
        const float* __restrict__ wout, const int* __restrict__ thrp,
        uint32_t* __restrict__ actPP, float* __restrict__ out,
        uint32_t* __restrict__ bar) {
    __shared__ uint2    tab[2 * H];                  // 128 KiB
    __shared__ uint32_t isg[S * HG * ISTRIDE];       // 17.5 KiB
    __shared__ uint32_t fbuf[8 * HG * 2];            // 2 KiB

    const int tid = threadIdx.x;
    const int bid = blockIdx.x;
    const int thr = load_threshold(thrp);

    // L1: input staged via global_load_lds (xPP from init dispatch)
    layer_phase<false, true>(xPP, idx0, signs0, actPP,
                             thr, bid, tid, tab, isg, fbuf);
    grid_barrier(bar, 1, tid);

    layer_phase<true, true>(actPP, idxH, signsH, actPP + (size_t)4 * H,
                            thr, bid, tid, tab, isg, fbuf);
    grid_barrier(bar, 2, tid);

    layer_phase<true, true>(actPP + (size_t)4 * H, idxH + (size_t)S * H * K,
                            signsH + (size_t)S * H * K, actPP + (size_t)8 * H,
                            thr, bid, tid, tab, isg, fbuf);
    grid_barrier(bar, 3, tid);

    // ---- final: 2048 waves = 128 b x 16 h-chunks (512 h each) ----
    {
        const int lane = tid & 63;
        const int gw   = bid * 8 + (tid >> 6);
        const int b    = gw >> 4;
        const int hc   = gw & 15;
        const int w32  = b >> 5;
        const int wp   = w32 >> 1;
        const int comp = w32 & 1;
        const int bit  = b & 31;

        float acc0 = 0.0f, acc1 = 0.0f;
        const int c1 = 64 + lane;
        const bool c1v = (c1 < C);

        for (int l = 0; l < L; ++l) {
            const uint32_t* aT = actPP + ((size_t)(l * 2 + wp) * H) * 2 + comp;
            const float* wl = wout + (size_t)l * H * C;
            for (int r = 0; r < 8; ++r) {
                const int hbase = hc * 512 + r * 64;
                const uint32_t m = AG_LOAD(&aT[(size_t)(hbase + lane) * 2]);
                uint64_t hm = __ballot((m >> bit) & 1u);
                while (hm) {
                    const int slot = __ffsll((unsigned long long)hm) - 1;
                    hm &= hm - 1;
                    const float* wr = wl + (size_t)(hbase + slot) * C;
                    acc0 += wr[lane];
                    if (c1v) acc1 += wr[c1];
                }
            }
        }
        atomicAdd(&out[b * C + lane], acc0);
        if (c1v) atomicAdd(&out[b * C + c1], acc1);
    }
}

// ---------------------------------------------------------------------------
// Fallback path (5 separate kernels, round-1 structure) in case the
// cooperative launch is rejected.
// ---------------------------------------------------------------------------
__global__ __launch_bounds__(512, 2) void layer_kernel(
        const uint32_t* __restrict__ prevPP, const int* __restrict__ idx,
        const float* __restrict__ signs, uint32_t* __restrict__ outPP,
        const int* __restrict__ thrp) {
    __shared__ uint2    tab[2 * H];
    __shared__ uint32_t isg[S * HG * ISTRIDE];
    __shared__ uint32_t fbuf[8 * HG * 2];
    layer_phase<false, false>(prevPP, idx, signs, outPP, load_threshold(thrp),
                              blockIdx.x, threadIdx.x, tab, isg, fbuf);
}

#define NHC 32
#define HCH (H / NHC)

__global__ void final_kernel(const uint32_t* __restrict__ actU,
                             const float* __restrict__ wout,
                             float* __restrict__ out) {
    const int lane = threadIdx.x & 63;
    const int wid  = threadIdx.x >> 6;
    const int hc   = blockIdx.x & (NHC - 1);
    const int bg   = blockIdx.x / NHC;
    const int b    = bg * 4 + wid;
    const int w32  = b >> 5;
    const int wp   = w32 >> 1;
    const int comp = w32 & 1;
    const int bit  = b & 31;

    float acc0 = 0.0f, acc1 = 0.0f;
    const int c1 = 64 + lane;
    const bool c1v = (c1 < C);

    for (int l = 0; l < L; ++l) {
        const uint32_t* aT = actU + ((size_t)(l * 2 + wp) * H) * 2 + comp;
        const float* wl = wout + (size_t)l * H * C;
        for (int r = 0; r < HCH / 64; ++r) {
            const int hbase = hc * HCH + r * 64;
            const uint32_t m = aT[(size_t)(hbase + lane) * 2];
            uint64_t hm = __ballot((m >> bit) & 1u);
            while (hm) {
                const int slot = __ffsll((unsigned long long)hm) - 1;
                hm &= hm - 1;
                const float* wr = wl + (size_t)(hbase + slot) * C;
                acc0 += wr[lane];
                if (c1v) acc1 += wr[c1];
            }
        }
    }
    atomicAdd(&out[b * C + lane], acc0);
    if (c1v) atomicAdd(&out[b * C + c1], acc1);
}

// ---------------------------------------------------------------------------
extern "C" void kernel_launch(void* const* d_in, const int* in_sizes, int n_in,
                              void* d_out, int out_size, void* d_ws, size_t ws_size,
                              hipStream_t stream) {
    const float* x      = (const float*)d_in[0];   // (B,F)
    const float* signs0 = (const float*)d_in[1];   // (S,H,K)
    const float* signsH = (const float*)d_in[2];   // (L-1,S,H,K)
    const float* wout   = (const float*)d_in[3];   // (L,H,C)
    const int*   idx0   = (const int*)d_in[4];     // (S,H,K)
    const int*   idxH   = (const int*)d_in[5];     // (L-1,S,H,K)
    const int*   thr    = (const int*)d_in[6];     // scalar
    float* out = (float*)d_out;                    // (B,C)

    // Workspace: xPP [2][F] uint2 (128 KiB), actPP [L][2][H] uint2 (384 KiB),
    // barrier state (2 u32 in separate lines)
    uint32_t* xPP   = (uint32_t*)d_ws;
    uint32_t* actPP = xPP + (size_t)4 * F;
    uint32_t* bar   = actPP + (size_t)12 * H;
    uint2*    xPP2  = (uint2*)d_ws;
    const uint32_t* xPPc = xPP;

    init_pack_kernel<<<F / 32, 128, 0, stream>>>(x, xPP2, out, bar);

    void* args[] = { (void*)&xPPc, (void*)&idx0, (void*)&signs0,
                     (void*)&idxH, (void*)&signsH, (void*)&wout, (void*)&thr,
                     (void*)&actPP, (void*)&out, (void*)&bar };
    hipError_t e = hipLaunchCooperativeKernel((const void*)fused_kernel,
                                              dim3(NBLK), dim3(NTHR),
                                              args, 0, stream);
    if (e != hipSuccess) {
        (void)hipGetLastError();   // clear, fall back to 5-dispatch path
        layer_kernel<<<H / HG, 512, 0, stream>>>(xPP, idx0, signs0, actPP, thr);
        layer_kernel<<<H / HG, 512, 0, stream>>>(actPP, idxH, signsH,
                                                 actPP + (size_t)4 * H, thr);
        layer_kernel<<<H / HG, 512, 0, stream>>>(actPP + (size_t)4 * H,
                                                 idxH + (size_t)S * H * K,
                                                 signsH + (size_t)S * H * K,
                                                 actPP + (size_t)8 * H, thr);
        final_kernel<<<32 * NHC, 256, 0, stream>>>(actPP, wout, out);
    }
}

// Round 5
// 129.170 us; speedup vs baseline: 2.8952x; 1.2813x over previous
//
#include <hip/hip_runtime.h>
#include <stdint.h>

#define B 128
#define F 8192
#define H 8192
#define S 4
#define K 32
#define L 3
#define C 100

#define NBLK 256
#define NTHR 512

// ---------------------------------------------------------------------------
// Planar-PAIR activation layout: plane (l, wp) is contiguous:
//   base u32 = (l*2 + wp) * 2 * H;  entry h = {word 2wp, word 2wp+1} uint2,
//   i.e. u32 index base + h*2 + comp.  Word w covers batches w*32..w*32+31,
//   bit = b & 31.  xPP uses the same per-wp plane layout (l = -1 analog).
// The network is INDEPENDENT per word-pair: layer l+1 plane wp depends only
// on layer l plane wp  ->  blocks and barriers are wp-scoped.
// ---------------------------------------------------------------------------

__device__ __forceinline__ int load_threshold(const int* p) {
    int v = *p;
    if (v >= (1 << 23)) v = (int)__int_as_float(v);
    return v;
}

// carry-save add of one 0/1-mask word into a 5-deep bit-sliced counter
__device__ __forceinline__ void cs5(uint32_t* a, uint32_t v) {
#pragma unroll
    for (int i = 0; i < 5; ++i) { const uint32_t t = a[i]; a[i] = t ^ v; v = t & v; }
}

// sum own 5-bit sliced counter with lane^32 partner's -> 6-bit result in y
__device__ __forceinline__ void pair_sum5(const uint32_t* x, uint32_t* y) {
    uint32_t c = 0;
#pragma unroll
    for (int i = 0; i < 5; ++i) {
        const uint32_t p = (uint32_t)__shfl_xor((int)x[i], 32);
        const uint32_t s = x[i] ^ p;
        y[i] = s ^ c;
        c = (x[i] & p) | (s & c);
    }
    y[5] = c;
}

// fired = (2P >= A + thr), bit-sliced over 7 bits; A,P are 6-deep (<=32)
__device__ __forceinline__ uint32_t fired_cmp(const uint32_t* A, const uint32_t* P, int thr) {
    uint32_t Y[7];
    uint32_t c = 0;
#pragma unroll
    for (int i = 0; i < 7; ++i) {
        const uint32_t ai = (i < 6) ? A[i] : 0u;
        const uint32_t bm = ((thr >> i) & 1) ? 0xFFFFFFFFu : 0u;
        const uint32_t t  = ai ^ bm;
        Y[i] = t ^ c;
        c = (ai & bm) | (t & c);
    }
    uint32_t bw = 0;
#pragma unroll
    for (int i = 0; i < 7; ++i) {
        const uint32_t xx = (i >= 1) ? P[i - 1] : 0u;
        const uint32_t d  = xx ^ Y[i];
        bw = ((~xx) & Y[i]) | ((~d) & bw);
    }
    return ~bw;
}

// async global->LDS, 16 B per lane
#define GLDS16(gp, lp)                                                \
    __builtin_amdgcn_global_load_lds(                                 \
        (const __attribute__((address_space(1))) uint32_t*)(gp),      \
        (__attribute__((address_space(3))) uint32_t*)(lp), 16, 0, 0)

#define AG_LOAD(p)                                                          \
    __hip_atomic_load((p), __ATOMIC_RELAXED, __HIP_MEMORY_SCOPE_AGENT)
#define AG_STORE(p, v)                                                      \
    __hip_atomic_store((p), (v), __ATOMIC_RELAXED, __HIP_MEMORY_SCOPE_AGENT)

// ---------------------------------------------------------------------------
// wp-scoped two-level pure-atomic barrier (128 blocks). NO device-scope
// fences: payload coherence is sc1 (LLC) stores + clean-L2-at-entry reads.
// wbar layout (u32): [g*16] 8 group counters (64 B apart, 16 blocks each),
// [128] root, [160] release flag.
// ---------------------------------------------------------------------------
__device__ __forceinline__ void wp_barrier(uint32_t* wbar, uint32_t ep,
                                           int tid, int gidx) {
    asm volatile("s_waitcnt vmcnt(0)" ::: "memory");   // payload stores at LLC
    __syncthreads();
    if (tid == 0) {
        const uint32_t t = __hip_atomic_fetch_add(&wbar[gidx * 16], 1u,
                               __ATOMIC_RELAXED, __HIP_MEMORY_SCOPE_AGENT) + 1u;
        if (t == ep * 16u) {
            const uint32_t r = __hip_atomic_fetch_add(&wbar[128], 1u,
                               __ATOMIC_RELAXED, __HIP_MEMORY_SCOPE_AGENT) + 1u;
            if (r == ep * 8u) AG_STORE(&wbar[160], ep);
        }
        int guard = 0;
        while (AG_LOAD(&wbar[160]) < ep) {
            __builtin_amdgcn_s_sleep(2);
            if (++guard > (1 << 17)) break;            // fail loud, don't hang
        }
    }
    __syncthreads();
    asm volatile("" ::: "memory");
}

// ---------------------------------------------------------------------------
// One layer, wp-split: block = 64 h-rows x 1 word-pair x 4 segments.
// 512 threads = 8 waves: wave (s = ww&3, rh = ww>>2); lane (h5 = lane&31,
// kh = lane>>5; K split 16/16, combined via shfl_xor(32)).
//  - tab: one 64 KiB plane via global_load_lds dwordx4 (8 rounds).
//  - idx/signs: straight to registers (each (s,h,k-half) used by exactly
//    one lane; 128 B-line coalesced across the wave) - no isg LDS at all.
//  - uint2 gathers feed carry-save counters for both words; bit-sliced
//    compare; OR across segments via fbuf; sc1 plane store.
// ---------------------------------------------------------------------------
__device__ __forceinline__ void layer_phase(
        const uint32_t* __restrict__ prevPlane,  // u32*, 2*H (one wp plane)
        const int* __restrict__ idx,             // (S,H,K)
        const float* __restrict__ signs,         // (S,H,K)
        uint32_t* __restrict__ outPlane,         // u32*, 2*H (one wp plane)
        const int thr, const int hg, const int tid,
        uint2* tab, uint32_t* fbuf) {
    const int lane = tid & 63;
    const int ww   = tid >> 6;
    const int s    = ww & 3;
    const int rh   = ww >> 2;
    const int kh   = lane >> 5;
    const int h5   = lane & 31;
    const int hloc = rh * 32 + h5;
    const int h    = hg * 64 + hloc;

    // ---- issue idx/sign register loads (overlap the GLDS staging) ----
    const size_t gb = ((size_t)s * H + h) * K + kh * 16;
    const int4   i0 = *(const int4*)(idx + gb);
    const int4   i1 = *(const int4*)(idx + gb + 4);
    const int4   i2 = *(const int4*)(idx + gb + 8);
    const int4   i3 = *(const int4*)(idx + gb + 12);
    const float4 s0 = *(const float4*)(signs + gb);
    const float4 s1 = *(const float4*)(signs + gb + 4);
    const float4 s2 = *(const float4*)(signs + gb + 8);
    const float4 s3 = *(const float4*)(signs + gb + 12);

    // ---- stage tab: 64 KiB plane, async direct-to-LDS ----
    {
        uint32_t* lbase = (uint32_t*)tab;
#pragma unroll
        for (int i = 0; i < 8; ++i) {
            const int o = (i * 512 + tid) * 4;      // u32 index, 16 B/lane
            GLDS16(prevPlane + o, lbase + o);
        }
    }
    __syncthreads();   // drains vmcnt (GLDS + reg loads)

    const uint32_t iv[16] = {
        (uint32_t)i0.x, (uint32_t)i0.y, (uint32_t)i0.z, (uint32_t)i0.w,
        (uint32_t)i1.x, (uint32_t)i1.y, (uint32_t)i1.z, (uint32_t)i1.w,
        (uint32_t)i2.x, (uint32_t)i2.y, (uint32_t)i2.z, (uint32_t)i2.w,
        (uint32_t)i3.x, (uint32_t)i3.y, (uint32_t)i3.z, (uint32_t)i3.w };
    const uint32_t pm[16] = {   // ~0 if sign positive
        ~(uint32_t)(__float_as_int(s0.x) >> 31), ~(uint32_t)(__float_as_int(s0.y) >> 31),
        ~(uint32_t)(__float_as_int(s0.z) >> 31), ~(uint32_t)(__float_as_int(s0.w) >> 31),
        ~(uint32_t)(__float_as_int(s1.x) >> 31), ~(uint32_t)(__float_as_int(s1.y) >> 31),
        ~(uint32_t)(__float_as_int(s1.z) >> 31), ~(uint32_t)(__float_as_int(s1.w) >> 31),
        ~(uint32_t)(__float_as_int(s2.x) >> 31), ~(uint32_t)(__float_as_int(s2.y) >> 31),
        ~(uint32_t)(__float_as_int(s2.z) >> 31), ~(uint32_t)(__float_as_int(s2.w) >> 31),
        ~(uint32_t)(__float_as_int(s3.x) >> 31), ~(uint32_t)(__float_as_int(s3.y) >> 31),
        ~(uint32_t)(__float_as_int(s3.z) >> 31), ~(uint32_t)(__float_as_int(s3.w) >> 31) };

    // ---- gather + bit-sliced accumulate (2 words per gather) ----
    uint32_t A0[5] = {0,0,0,0,0}, P0[5] = {0,0,0,0,0};
    uint32_t A1[5] = {0,0,0,0,0}, P1[5] = {0,0,0,0,0};
#pragma unroll
    for (int c8 = 0; c8 < 2; ++c8) {
        uint2 g[8];
#pragma unroll
        for (int j = 0; j < 8; ++j) g[j] = tab[iv[c8 * 8 + j]];
#pragma unroll
        for (int j = 0; j < 8; ++j) {
            const uint32_t pmv = pm[c8 * 8 + j];
            cs5(A0, g[j].x);
            cs5(P0, g[j].x & pmv);
            cs5(A1, g[j].y);
            cs5(P1, g[j].y & pmv);
        }
    }

    // ---- combine k halves (lane^32) -> 6-bit counters ----
    uint32_t A0f[6], P0f[6], A1f[6], P1f[6];
    pair_sum5(A0, A0f);
    pair_sum5(P0, P0f);
    pair_sum5(A1, A1f);
    pair_sum5(P1, P1f);

    const uint32_t f0 = fired_cmp(A0f, P0f, thr);   // word 2wp
    const uint32_t f1 = fired_cmp(A1f, P1f, thr);   // word 2wp+1

    if (kh == 0) {
        fbuf[((s * 2 + rh) * 32 + h5) * 2 + 0] = f0;
        fbuf[((s * 2 + rh) * 32 + h5) * 2 + 1] = f1;
    }
    __syncthreads();

    // ---- OR across 4 segments, write 128 consecutive u32 (sc1) ----
    if (tid < 128) {
        const int rr   = tid >> 6;           // rh
        const int hh   = (tid >> 1) & 31;    // h5
        const int comp = tid & 1;
        uint32_t v = 0;
#pragma unroll
        for (int s2 = 0; s2 < 4; ++s2)
            v |= fbuf[((s2 * 2 + rr) * 32 + hh) * 2 + comp];
        AG_STORE(&outPlane[(size_t)(hg * 64 + rr * 32 + hh) * 2 + comp], v);
    }
}

// ---------------------------------------------------------------------------
// Init kernel (normal dispatch): zero out + barrier state, pack x -> xPP
// planes. 256 blocks x 128 threads (thread = b), 32 f per block. Dispatch
// boundary makes xPP/out/bar coherent for the fused kernel.
// ---------------------------------------------------------------------------
__global__ __launch_bounds__(128) void init_pack_kernel(
        const float* __restrict__ x, uint2* __restrict__ xPP,
        float* __restrict__ out, uint32_t* __restrict__ bar) {
    const int zi = blockIdx.x * 128 + threadIdx.x;
    if (zi < B * C) out[zi] = 0.0f;
    if (blockIdx.x < 4) bar[blockIdx.x * 128 + threadIdx.x] = 0u;

    const int b  = threadIdx.x;          // 0..127
    const int wv = threadIdx.x >> 6;     // word pair (0,1)
    const int f0 = blockIdx.x * 32;
    const float4* xr = (const float4*)(x + (size_t)b * F + f0);
    for (int j = 0; j < 8; ++j) {
        const float4 v = xr[j];
        const uint64_t m0 = __ballot(v.x > 0.5f);
        const uint64_t m1 = __ballot(v.y > 0.5f);
        const uint64_t m2 = __ballot(v.z > 0.5f);
        const uint64_t m3 = __ballot(v.w > 0.5f);
        if ((threadIdx.x & 63) == 0) {
            const int f = f0 + 4 * j;
            uint4* dst = (uint4*)(xPP + (size_t)wv * F + f);
            dst[0] = make_uint4((uint32_t)m0, (uint32_t)(m0 >> 32),
                                (uint32_t)m1, (uint32_t)(m1 >> 32));
            dst[1] = make_uint4((uint32_t)m2, (uint32_t)(m2 >> 32),
                                (uint32_t)m3, (uint32_t)(m3 >> 32));
        }
    }
}

// ---------------------------------------------------------------------------
// FUSED kernel, NORMAL launch: 256 blocks x 512 threads. LDS = 66 KiB ->
// 2 blocks/CU CAPACITY (512 slots for 256 blocks): co-residency holds even
// with half the device unavailable. __launch_bounds__(512,4) caps VGPR at
// 128 so the 2-blocks/CU capacity is real. Block = (hg = bid>>1, wp = bid&1);
// barriers are wp-scoped (128 blocks). L1 | bar | L2 | bar | L3 | bar | final.
// ---------------------------------------------------------------------------
__global__ __launch_bounds__(512, 4) void fused_kernel(
        const uint32_t* __restrict__ xPP,      // [2][F] uint2 planes, as u32*
        const int* __restrict__ idx0, const float* __restrict__ signs0,
        const int* __restrict__ idxH, const float* __restrict__ signsH,
        const float* __restrict__ wout, const int* __restrict__ thrp,
        uint32_t* __restrict__ actPP, float* __restrict__ out,
        uint32_t* __restrict__ bar) {
    __shared__ uint2    tab[H];                  // 64 KiB (one wp plane)
    __shared__ uint32_t fbuf[4 * 2 * 32 * 2];    // 2 KiB

    const int tid = threadIdx.x;
    const int bid = blockIdx.x;
    const int wp  = bid & 1;
    const int hg  = bid >> 1;                    // 0..127 (64 h-rows each)
    const int thr = load_threshold(thrp);

    uint32_t* wbar = bar + wp * 256;
    const int gidx = (bid >> 1) & 7;             // 16 blocks per group

    const uint32_t* xPlane = xPP + (size_t)wp * 2 * F;
    uint32_t* pl0 = actPP + (size_t)(0 * 2 + wp) * 2 * H;
    uint32_t* pl1 = actPP + (size_t)(1 * 2 + wp) * 2 * H;
    uint32_t* pl2 = actPP + (size_t)(2 * 2 + wp) * 2 * H;

    const int*   idx2   = idxH;
    const float* signs2 = signsH;
    const int*   idx3   = idxH + (size_t)S * H * K;
    const float* signs3 = signsH + (size_t)S * H * K;

    layer_phase(xPlane, idx0, signs0, pl0, thr, hg, tid, tab, fbuf);
    wp_barrier(wbar, 1, tid, gidx);

    layer_phase(pl0, idx2, signs2, pl1, thr, hg, tid, tab, fbuf);
    wp_barrier(wbar, 2, tid, gidx);

    layer_phase(pl1, idx3, signs3, pl2, thr, hg, tid, tab, fbuf);
    wp_barrier(wbar, 3, tid, gidx);

    // ---- final: 2048 waves = 128 b x 16 h-chunks (512 h each) ----
    {
        const int lane = tid & 63;
        const int gw   = bid * 8 + (tid >> 6);
        const int b    = gw >> 4;
        const int hc   = gw & 15;
        const int w32  = b >> 5;
        const int fwp  = w32 >> 1;
        const int comp = w32 & 1;
        const int bit  = b & 31;

        // prefetch all 24 mask words up front (hide LLC latency once)
        uint32_t mv[L][8];
#pragma unroll
        for (int l = 0; l < L; ++l) {
            const uint32_t* aT = actPP + (size_t)(l * 2 + fwp) * 2 * H + comp;
#pragma unroll
            for (int r = 0; r < 8; ++r)
                mv[l][r] = AG_LOAD(&aT[(size_t)(hc * 512 + r * 64 + lane) * 2]);
        }

        float acc0 = 0.0f, acc1 = 0.0f;
        const int c1 = 64 + lane;
        const bool c1v = (c1 < C);

#pragma unroll
        for (int l = 0; l < L; ++l) {
            const float* wl = wout + (size_t)l * H * C;
#pragma unroll
            for (int r = 0; r < 8; ++r) {
                const int hbase = hc * 512 + r * 64;
                uint64_t hm = __ballot((mv[l][r] >> bit) & 1u);
                while (hm) {
                    const int slot = __ffsll((unsigned long long)hm) - 1;
                    hm &= hm - 1;
                    const float* wr = wl + (size_t)(hbase + slot) * C;
                    acc0 += wr[lane];
                    if (c1v) acc1 += wr[c1];
                }
            }
        }
        atomicAdd(&out[b * C + lane], acc0);
        if (c1v) atomicAdd(&out[b * C + c1], acc1);
    }
}

// ---------------------------------------------------------------------------
extern "C" void kernel_launch(void* const* d_in, const int* in_sizes, int n_in,
                              void* d_out, int out_size, void* d_ws, size_t ws_size,
                              hipStream_t stream) {
    const float* x      = (const float*)d_in[0];   // (B,F)
    const float* signs0 = (const float*)d_in[1];   // (S,H,K)
    const float* signsH = (const float*)d_in[2];   // (L-1,S,H,K)
    const float* wout   = (const float*)d_in[3];   // (L,H,C)
    const int*   idx0   = (const int*)d_in[4];     // (S,H,K)
    const int*   idxH   = (const int*)d_in[5];     // (L-1,S,H,K)
    const int*   thr    = (const int*)d_in[6];     // scalar
    float* out = (float*)d_out;                    // (B,C)

    // Workspace: xPP [2][F] uint2 (128 KiB), actPP [L][2][H] uint2 (384 KiB),
    // barrier state (512 u32)
    uint32_t* xPP   = (uint32_t*)d_ws;
    uint32_t* actPP = xPP + (size_t)4 * F;
    uint32_t* bar   = actPP + (size_t)12 * H;
    uint2*    xPP2  = (uint2*)d_ws;

    init_pack_kernel<<<F / 32, 128, 0, stream>>>(x, xPP2, out, bar);
    fused_kernel<<<NBLK, NTHR, 0, stream>>>(xPP, idx0, signs0, idxH, signsH,
                                            wout, thr, actPP, out, bar);
}

// Round 6
// 118.598 us; speedup vs baseline: 3.1533x; 1.0891x over previous
//
#include <hip/hip_runtime.h>
#include <stdint.h>

#define B 128
#define F 8192
#define H 8192
#define S 4
#define K 32
#define L 3
#define C 100

#define NBLK 256
#define NTHR 512

// ---------------------------------------------------------------------------
// Planar-PAIR activation layout: plane (l, wp) is contiguous:
//   base u32 = (l*2 + wp) * 2 * H;  entry h = {word 2wp, word 2wp+1} uint2.
// Word w covers batches w*32..w*32+31, bit = b & 31. xPP analogous.
// Network is INDEPENDENT per word-pair -> blocks/barriers are wp-scoped.
// ---------------------------------------------------------------------------

__device__ __forceinline__ int load_threshold(const int* p) {
    int v = *p;
    if (v >= (1 << 23)) v = (int)__int_as_float(v);
    return v;
}

// carry-save add of one 0/1-mask word into a 5-deep bit-sliced counter
__device__ __forceinline__ void cs5(uint32_t* a, uint32_t v) {
#pragma unroll
    for (int i = 0; i < 5; ++i) { const uint32_t t = a[i]; a[i] = t ^ v; v = t & v; }
}

// sum own 5-bit sliced counter with lane^32 partner's -> 6-bit result in y
__device__ __forceinline__ void pair_sum5(const uint32_t* x, uint32_t* y) {
    uint32_t c = 0;
#pragma unroll
    for (int i = 0; i < 5; ++i) {
        const uint32_t p = (uint32_t)__shfl_xor((int)x[i], 32);
        const uint32_t s = x[i] ^ p;
        y[i] = s ^ c;
        c = (x[i] & p) | (s & c);
    }
    y[5] = c;
}

// fired = (2P >= A + thr), bit-sliced over 7 bits; A,P are 6-deep (<=32)
__device__ __forceinline__ uint32_t fired_cmp(const uint32_t* A, const uint32_t* P, int thr) {
    uint32_t Y[7];
    uint32_t c = 0;
#pragma unroll
    for (int i = 0; i < 7; ++i) {
        const uint32_t ai = (i < 6) ? A[i] : 0u;
        const uint32_t bm = ((thr >> i) & 1) ? 0xFFFFFFFFu : 0u;
        const uint32_t t  = ai ^ bm;
        Y[i] = t ^ c;
        c = (ai & bm) | (t & c);
    }
    uint32_t bw = 0;
#pragma unroll
    for (int i = 0; i < 7; ++i) {
        const uint32_t xx = (i >= 1) ? P[i - 1] : 0u;
        const uint32_t d  = xx ^ Y[i];
        bw = ((~xx) & Y[i]) | ((~d) & bw);
    }
    return ~bw;
}

// async global->LDS, 16 B per lane
#define GLDS16(gp, lp)                                                \
    __builtin_amdgcn_global_load_lds(                                 \
        (const __attribute__((address_space(1))) uint32_t*)(gp),      \
        (__attribute__((address_space(3))) uint32_t*)(lp), 16, 0, 0)

#define AG_LOAD(p)                                                          \
    __hip_atomic_load((p), __ATOMIC_RELAXED, __HIP_MEMORY_SCOPE_AGENT)
#define AG_STORE(p, v)                                                      \
    __hip_atomic_store((p), (v), __ATOMIC_RELAXED, __HIP_MEMORY_SCOPE_AGENT)

// ---------------------------------------------------------------------------
// Barrier state (u32 indices into bar):
//   wp region = wp*1024: group counters [g*32] g=0..7 (16 blocks each),
//   root [256], release flags [512 + g*32].
//   Magic handshake (shared): [2048]=MAGIC_A, [2049]=MAGIC_B — published by
//   block 0 AFTER zeroing all counters (vmcnt-ordered). Workspace is
//   re-poisoned by the harness each iteration; no uniform fill pattern can
//   equal two DIFFERENT magic words, and re-poison kills stale state.
// ---------------------------------------------------------------------------
#define MAGIC_A 0x3C6EF372u
#define MAGIC_B 0xDAA66D2Bu
#define MAG_IDX 2048

__device__ __forceinline__ void wp_barrier(uint32_t* bar, int wp, uint32_t ep,
                                           int tid, int gidx, bool first) {
    asm volatile("s_waitcnt vmcnt(0)" ::: "memory");   // payload stores at LLC
    __syncthreads();
    if (tid == 0) {
        uint32_t* wbar = bar + wp * 1024;
        int guard = 0;
        if (first) {   // wait for block 0's counter-zero + magic publish
            while (AG_LOAD(&bar[MAG_IDX]) != MAGIC_A ||
                   AG_LOAD(&bar[MAG_IDX + 1]) != MAGIC_B) {
                __builtin_amdgcn_s_sleep(2);
                if (++guard > (1 << 18)) break;        // fail loud, don't hang
            }
        }
        const uint32_t t = __hip_atomic_fetch_add(&wbar[gidx * 32], 1u,
                               __ATOMIC_RELAXED, __HIP_MEMORY_SCOPE_AGENT) + 1u;
        if (t == ep * 16u) {
            const uint32_t r = __hip_atomic_fetch_add(&wbar[256], 1u,
                               __ATOMIC_RELAXED, __HIP_MEMORY_SCOPE_AGENT) + 1u;
            if (r == ep * 8u) {
#pragma unroll
                for (int g = 0; g < 8; ++g) AG_STORE(&wbar[512 + g * 32], ep);
            }
        }
        guard = 0;
        while (AG_LOAD(&wbar[512 + gidx * 32]) < ep) {
            __builtin_amdgcn_s_sleep(2);
            if (++guard > (1 << 18)) break;            // fail loud, don't hang
        }
    }
    __syncthreads();
    asm volatile("" ::: "memory");
}

// ---------------------------------------------------------------------------
// One layer, wp-split: block = 64 h-rows x 1 word-pair x 4 segments.
// 512 threads = 8 waves: wave (s = ww&3, rh = ww>>2); lane (h5 = lane&31,
// kh = lane>>5; K split 16/16, combined via shfl_xor(32)).
//  - tab: one 64 KiB plane via global_load_lds dwordx4 (8 rounds).
//  - idx/signs: straight to registers (coalesced 128 B lines per wave).
//  - uint2 gathers feed carry-save counters for both words; bit-sliced
//    compare; OR across segments via fbuf; sc1 plane store.
// ---------------------------------------------------------------------------
__device__ __forceinline__ void layer_phase(
        const uint32_t* __restrict__ prevPlane,  // u32*, 2*H (one wp plane)
        const int* __restrict__ idx,             // (S,H,K)
        const float* __restrict__ signs,         // (S,H,K)
        uint32_t* __restrict__ outPlane,         // u32*, 2*H (one wp plane)
        const int thr, const int hg, const int tid,
        uint2* tab, uint32_t* fbuf) {
    const int lane = tid & 63;
    const int ww   = tid >> 6;
    const int s    = ww & 3;
    const int rh   = ww >> 2;
    const int kh   = lane >> 5;
    const int h5   = lane & 31;
    const int h    = hg * 64 + rh * 32 + h5;

    // ---- issue idx/sign register loads (overlap the GLDS staging) ----
    const size_t gb = ((size_t)s * H + h) * K + kh * 16;
    const int4   i0 = *(const int4*)(idx + gb);
    const int4   i1 = *(const int4*)(idx + gb + 4);
    const int4   i2 = *(const int4*)(idx + gb + 8);
    const int4   i3 = *(const int4*)(idx + gb + 12);
    const float4 s0 = *(const float4*)(signs + gb);
    const float4 s1 = *(const float4*)(signs + gb + 4);
    const float4 s2 = *(const float4*)(signs + gb + 8);
    const float4 s3 = *(const float4*)(signs + gb + 12);

    // ---- stage tab: 64 KiB plane, async direct-to-LDS ----
    {
        uint32_t* lbase = (uint32_t*)tab;
#pragma unroll
        for (int i = 0; i < 8; ++i) {
            const int o = (i * 512 + tid) * 4;      // u32 index, 16 B/lane
            GLDS16(prevPlane + o, lbase + o);
        }
    }
    __syncthreads();   // drains vmcnt (GLDS + reg loads)

    const uint32_t iv[16] = {
        (uint32_t)i0.x, (uint32_t)i0.y, (uint32_t)i0.z, (uint32_t)i0.w,
        (uint32_t)i1.x, (uint32_t)i1.y, (uint32_t)i1.z, (uint32_t)i1.w,
        (uint32_t)i2.x, (uint32_t)i2.y, (uint32_t)i2.z, (uint32_t)i2.w,
        (uint32_t)i3.x, (uint32_t)i3.y, (uint32_t)i3.z, (uint32_t)i3.w };
    const uint32_t pm[16] = {   // ~0 if sign positive
        ~(uint32_t)(__float_as_int(s0.x) >> 31), ~(uint32_t)(__float_as_int(s0.y) >> 31),
        ~(uint32_t)(__float_as_int(s0.z) >> 31), ~(uint32_t)(__float_as_int(s0.w) >> 31),
        ~(uint32_t)(__float_as_int(s1.x) >> 31), ~(uint32_t)(__float_as_int(s1.y) >> 31),
        ~(uint32_t)(__float_as_int(s1.z) >> 31), ~(uint32_t)(__float_as_int(s1.w) >> 31),
        ~(uint32_t)(__float_as_int(s2.x) >> 31), ~(uint32_t)(__float_as_int(s2.y) >> 31),
        ~(uint32_t)(__float_as_int(s2.z) >> 31), ~(uint32_t)(__float_as_int(s2.w) >> 31),
        ~(uint32_t)(__float_as_int(s3.x) >> 31), ~(uint32_t)(__float_as_int(s3.y) >> 31),
        ~(uint32_t)(__float_as_int(s3.z) >> 31), ~(uint32_t)(__float_as_int(s3.w) >> 31) };

    // ---- gather + bit-sliced accumulate (2 words per gather) ----
    uint32_t A0[5] = {0,0,0,0,0}, P0[5] = {0,0,0,0,0};
    uint32_t A1[5] = {0,0,0,0,0}, P1[5] = {0,0,0,0,0};
#pragma unroll
    for (int c8 = 0; c8 < 2; ++c8) {
        uint2 g[8];
#pragma unroll
        for (int j = 0; j < 8; ++j) g[j] = tab[iv[c8 * 8 + j]];
#pragma unroll
        for (int j = 0; j < 8; ++j) {
            const uint32_t pmv = pm[c8 * 8 + j];
            cs5(A0, g[j].x);
            cs5(P0, g[j].x & pmv);
            cs5(A1, g[j].y);
            cs5(P1, g[j].y & pmv);
        }
    }

    // ---- combine k halves (lane^32) -> 6-bit counters ----
    uint32_t A0f[6], P0f[6], A1f[6], P1f[6];
    pair_sum5(A0, A0f);
    pair_sum5(P0, P0f);
    pair_sum5(A1, A1f);
    pair_sum5(P1, P1f);

    const uint32_t f0 = fired_cmp(A0f, P0f, thr);   // word 2wp
    const uint32_t f1 = fired_cmp(A1f, P1f, thr);   // word 2wp+1

    if (kh == 0) {
        fbuf[((s * 2 + rh) * 32 + h5) * 2 + 0] = f0;
        fbuf[((s * 2 + rh) * 32 + h5) * 2 + 1] = f1;
    }
    __syncthreads();

    // ---- OR across 4 segments, write 128 consecutive u32 (sc1) ----
    if (tid < 128) {
        const int rr   = tid >> 6;           // rh
        const int hh   = (tid >> 1) & 31;    // h5
        const int comp = tid & 1;
        uint32_t v = 0;
#pragma unroll
        for (int s2 = 0; s2 < 4; ++s2)
            v |= fbuf[((s2 * 2 + rr) * 32 + hh) * 2 + comp];
        AG_STORE(&outPlane[(size_t)(hg * 64 + rr * 32 + hh) * 2 + comp], v);
    }
}

// ---------------------------------------------------------------------------
// SINGLE fused kernel, NORMAL launch: 256 blocks x 512 threads, 66 KiB LDS
// -> 2 blocks/CU capacity (co-residency robust even at half the device).
// Block = (hg = bid>>1, wp = bid&1); barriers wp-scoped (128 blocks).
// P0 pack+zero(+bar-init by block 0) | bar1 | L1 | bar2 | L2 | bar3 | L3 |
// bar4 | final (progressive mask prefetch, 8-wide batched wout gathers).
// ---------------------------------------------------------------------------
__global__ __launch_bounds__(512, 4) void fused_kernel(
        const float* __restrict__ x,
        const int* __restrict__ idx0, const float* __restrict__ signs0,
        const int* __restrict__ idxH, const float* __restrict__ signsH,
        const float* __restrict__ wout, const int* __restrict__ thrp,
        uint32_t* __restrict__ xPP,     // [2][F] uint2 planes, as u32*
        uint32_t* __restrict__ actPP, float* __restrict__ out,
        uint32_t* __restrict__ bar) {
    __shared__ uint2    tab[H];                  // 64 KiB (one wp plane)
    __shared__ uint32_t fbuf[4 * 2 * 32 * 2];    // 2 KiB

    const int tid = threadIdx.x;
    const int bid = blockIdx.x;
    const int wp  = bid & 1;
    const int hg  = bid >> 1;                    // 0..127 (64 h-rows each)
    const int gidx = hg & 7;                     // 16 blocks/group/wp
    const int thr = load_threshold(thrp);

    // ---- block 0: zero barrier counters, publish magic (vmcnt-ordered) ----
    if (bid == 0) {
#pragma unroll
        for (int i = 0; i < 4; ++i) AG_STORE(&bar[i * 512 + tid], 0u);
        asm volatile("s_waitcnt vmcnt(0)" ::: "memory");
        __syncthreads();
        if (tid == 0) {
            AG_STORE(&bar[MAG_IDX], MAGIC_A);
            AG_STORE(&bar[MAG_IDX + 1], MAGIC_B);
        }
    }

    // ---- P0: zero out (sc1) + pack x -> xPP (sc1) ----
    {
        const int zi = bid * 512 + tid;
        if (zi < B * C) AG_STORE((uint32_t*)&out[zi], 0u);

        const int b   = tid & 127;
        const int wv  = (tid >> 6) & 1;       // word pair of this wave
        const int sub = tid >> 7;             // 0..3 -> j = 2*sub..2*sub+1
        const int f0  = bid * 32;
        const float4* xr = (const float4*)(x + (size_t)b * F + f0);
#pragma unroll
        for (int jj = 0; jj < 2; ++jj) {
            const int j = sub * 2 + jj;
            const float4 v = xr[j];
            const uint64_t m0 = __ballot(v.x > 0.5f);
            const uint64_t m1 = __ballot(v.y > 0.5f);
            const uint64_t m2 = __ballot(v.z > 0.5f);
            const uint64_t m3 = __ballot(v.w > 0.5f);
            if ((tid & 63) == 0) {
                const int f = f0 + 4 * j;
                unsigned long long* q =
                    (unsigned long long*)(xPP + ((size_t)wv * F + f) * 2);
                AG_STORE(q + 0, (unsigned long long)m0);
                AG_STORE(q + 1, (unsigned long long)m1);
                AG_STORE(q + 2, (unsigned long long)m2);
                AG_STORE(q + 3, (unsigned long long)m3);
            }
        }
    }
    wp_barrier(bar, wp, 1, tid, gidx, true);

    const uint32_t* xPlane = xPP + (size_t)wp * 2 * F;
    uint32_t* pl0 = actPP + (size_t)(0 * 2 + wp) * 2 * H;
    uint32_t* pl1 = actPP + (size_t)(1 * 2 + wp) * 2 * H;
    uint32_t* pl2 = actPP + (size_t)(2 * 2 + wp) * 2 * H;
    const int*   idx2   = idxH;
    const float* signs2 = signsH;
    const int*   idx3   = idxH + (size_t)S * H * K;
    const float* signs3 = signsH + (size_t)S * H * K;

    // final-phase geometry (used for progressive mask prefetch)
    const int lane = tid & 63;
    const int gw   = bid * 8 + (tid >> 6);
    const int fb   = gw >> 4;                    // batch b
    const int hc   = gw & 15;                    // h-chunk (512 h)
    const int w32  = fb >> 5;
    const int fwp  = w32 >> 1;
    const int comp = w32 & 1;
    const int bit  = fb & 31;
    uint32_t mv[L][8];

    layer_phase(xPlane, idx0, signs0, pl0, thr, hg, tid, tab, fbuf);
    wp_barrier(bar, wp, 2, tid, gidx, false);

    {   // prefetch l=0 masks (pl0 ready); hides under L2
        const uint32_t* aT = actPP + (size_t)(0 * 2 + fwp) * 2 * H + comp;
#pragma unroll
        for (int r = 0; r < 8; ++r)
            mv[0][r] = AG_LOAD(&aT[(size_t)(hc * 512 + r * 64 + lane) * 2]);
    }
    layer_phase(pl0, idx2, signs2, pl1, thr, hg, tid, tab, fbuf);
    wp_barrier(bar, wp, 3, tid, gidx, false);

    {   // prefetch l=1 masks (pl1 ready); hides under L3
        const uint32_t* aT = actPP + (size_t)(1 * 2 + fwp) * 2 * H + comp;
#pragma unroll
        for (int r = 0; r < 8; ++r)
            mv[1][r] = AG_LOAD(&aT[(size_t)(hc * 512 + r * 64 + lane) * 2]);
    }
    layer_phase(pl1, idx3, signs3, pl2, thr, hg, tid, tab, fbuf);
    wp_barrier(bar, wp, 4, tid, gidx, false);

    {   // prefetch l=2 masks
        const uint32_t* aT = actPP + (size_t)(2 * 2 + fwp) * 2 * H + comp;
#pragma unroll
        for (int r = 0; r < 8; ++r)
            mv[2][r] = AG_LOAD(&aT[(size_t)(hc * 512 + r * 64 + lane) * 2]);
    }

    // ---- final: wave = (b, hc); 8-wide batched gather of wout rows ----
    {
        float acc0 = 0.0f, acc1 = 0.0f;
        const int c1 = 64 + lane;
        const bool c1v = (c1 < C);

#pragma unroll
        for (int l = 0; l < L; ++l) {
            const float* wl = wout + (size_t)l * H * C;
#pragma unroll
            for (int r = 0; r < 8; ++r) {
                const int hbase = hc * 512 + r * 64;
                uint64_t hm = __ballot((mv[l][r] >> bit) & 1u);
                while (hm) {
                    int sl[8];
#pragma unroll
                    for (int i = 0; i < 8; ++i) {   // extract up to 8 slots
                        sl[i] = hm ? (__ffsll((unsigned long long)hm) - 1) : -1;
                        hm &= hm - 1;
                    }
                    float v0[8], v1[8];
#pragma unroll
                    for (int i = 0; i < 8; ++i) {   // batched independent loads
                        if (sl[i] >= 0) {
                            const float* wr = wl + (size_t)(hbase + sl[i]) * C;
                            v0[i] = wr[lane];
                            v1[i] = c1v ? wr[c1] : 0.0f;
                        } else { v0[i] = 0.0f; v1[i] = 0.0f; }
                    }
#pragma unroll
                    for (int i = 0; i < 8; ++i) { acc0 += v0[i]; acc1 += v1[i]; }
                }
            }
        }
        atomicAdd(&out[fb * C + lane], acc0);
        if (c1v) atomicAdd(&out[fb * C + c1], acc1);
    }
}

// ---------------------------------------------------------------------------
extern "C" void kernel_launch(void* const* d_in, const int* in_sizes, int n_in,
                              void* d_out, int out_size, void* d_ws, size_t ws_size,
                              hipStream_t stream) {
    const float* x      = (const float*)d_in[0];   // (B,F)
    const float* signs0 = (const float*)d_in[1];   // (S,H,K)
    const float* signsH = (const float*)d_in[2];   // (L-1,S,H,K)
    const float* wout   = (const float*)d_in[3];   // (L,H,C)
    const int*   idx0   = (const int*)d_in[4];     // (S,H,K)
    const int*   idxH   = (const int*)d_in[5];     // (L-1,S,H,K)
    const int*   thr    = (const int*)d_in[6];     // scalar
    float* out = (float*)d_out;                    // (B,C)

    // Workspace: xPP [2][F] uint2 (128 KiB), actPP [L][2][H] uint2 (384 KiB),
    // barrier state (2 wp x 1024 u32 + magic line)
    uint32_t* xPP   = (uint32_t*)d_ws;
    uint32_t* actPP = xPP + (size_t)4 * F;
    uint32_t* bar   = actPP + (size_t)12 * H;

    fused_kernel<<<NBLK, NTHR, 0, stream>>>(x, idx0, signs0, idxH, signsH,
                                            wout, thr, xPP, actPP, out, bar);
}

// Round 7
// 118.282 us; speedup vs baseline: 3.1617x; 1.0027x over previous
//
#include <hip/hip_runtime.h>
#include <stdint.h>

#define B 128
#define F 8192
#define H 8192
#define S 4
#define K 32
#define L 3
#define C 100

#define NBLK 256
#define NTHR 512

// ---------------------------------------------------------------------------
// Planar-PAIR activation layout: plane (l, wp) is contiguous:
//   base u32 = (l*2 + wp) * 2 * H;  entry h = {word 2wp, word 2wp+1} uint2.
// Word w covers batches w*32..w*32+31, bit = b & 31. xPP analogous.
// Network is INDEPENDENT per word-pair -> blocks/barriers are wp-scoped.
// ---------------------------------------------------------------------------

__device__ __forceinline__ int load_threshold(const int* p) {
    int v = *p;
    if (v >= (1 << 23)) v = (int)__int_as_float(v);
    return v;
}

// carry-save add of one 0/1-mask word into a 5-deep bit-sliced counter
__device__ __forceinline__ void cs5(uint32_t* a, uint32_t v) {
#pragma unroll
    for (int i = 0; i < 5; ++i) { const uint32_t t = a[i]; a[i] = t ^ v; v = t & v; }
}

// sum own 5-bit sliced counter with lane^32 partner's -> 6-bit result in y
__device__ __forceinline__ void pair_sum5(const uint32_t* x, uint32_t* y) {
    uint32_t c = 0;
#pragma unroll
    for (int i = 0; i < 5; ++i) {
        const uint32_t p = (uint32_t)__shfl_xor((int)x[i], 32);
        const uint32_t s = x[i] ^ p;
        y[i] = s ^ c;
        c = (x[i] & p) | (s & c);
    }
    y[5] = c;
}

// fired = (2P >= A + thr), bit-sliced over 7 bits; A,P are 6-deep (<=32)
__device__ __forceinline__ uint32_t fired_cmp(const uint32_t* A, const uint32_t* P, int thr) {
    uint32_t Y[7];
    uint32_t c = 0;
#pragma unroll
    for (int i = 0; i < 7; ++i) {
        const uint32_t ai = (i < 6) ? A[i] : 0u;
        const uint32_t bm = ((thr >> i) & 1) ? 0xFFFFFFFFu : 0u;
        const uint32_t t  = ai ^ bm;
        Y[i] = t ^ c;
        c = (ai & bm) | (t & c);
    }
    uint32_t bw = 0;
#pragma unroll
    for (int i = 0; i < 7; ++i) {
        const uint32_t xx = (i >= 1) ? P[i - 1] : 0u;
        const uint32_t d  = xx ^ Y[i];
        bw = ((~xx) & Y[i]) | ((~d) & bw);
    }
    return ~bw;
}

// async global->LDS, 16 B per lane
#define GLDS16(gp, lp)                                                \
    __builtin_amdgcn_global_load_lds(                                 \
        (const __attribute__((address_space(1))) uint32_t*)(gp),      \
        (__attribute__((address_space(3))) uint32_t*)(lp), 16, 0, 0)

#define AG_LOAD(p)                                                          \
    __hip_atomic_load((p), __ATOMIC_RELAXED, __HIP_MEMORY_SCOPE_AGENT)
#define AG_STORE(p, v)                                                      \
    __hip_atomic_store((p), (v), __ATOMIC_RELAXED, __HIP_MEMORY_SCOPE_AGENT)

// ---------------------------------------------------------------------------
// Barrier state (u32 indices into bar):
//   wp region = wp*1024: group counters [g*32] g=0..7 (16 blocks each),
//   root [256], release flags [512 + g*32].
//   Magic handshake (shared): [2048]=MAGIC_A, [2049]=MAGIC_B — published by
//   block 0 AFTER zeroing all counters (vmcnt-ordered). Workspace re-poison
//   can't fake two DIFFERENT magic words with a uniform fill, and re-poison
//   kills stale state between iterations.
// ---------------------------------------------------------------------------
#define MAGIC_A 0x3C6EF372u
#define MAGIC_B 0xDAA66D2Bu
#define MAG_IDX 2048

__device__ __forceinline__ void wp_barrier(uint32_t* bar, int wp, uint32_t ep,
                                           int tid, int gidx, bool first) {
    asm volatile("s_waitcnt vmcnt(0)" ::: "memory");   // payload stores at LLC
    __syncthreads();
    if (tid == 0) {
        uint32_t* wbar = bar + wp * 1024;
        int guard = 0;
        if (first) {   // wait for block 0's counter-zero + magic publish
            while (AG_LOAD(&bar[MAG_IDX]) != MAGIC_A ||
                   AG_LOAD(&bar[MAG_IDX + 1]) != MAGIC_B) {
                __builtin_amdgcn_s_sleep(2);
                if (++guard > (1 << 18)) break;        // fail loud, don't hang
            }
        }
        const uint32_t t = __hip_atomic_fetch_add(&wbar[gidx * 32], 1u,
                               __ATOMIC_RELAXED, __HIP_MEMORY_SCOPE_AGENT) + 1u;
        if (t == ep * 16u) {
            const uint32_t r = __hip_atomic_fetch_add(&wbar[256], 1u,
                               __ATOMIC_RELAXED, __HIP_MEMORY_SCOPE_AGENT) + 1u;
            if (r == ep * 8u) {
#pragma unroll
                for (int g = 0; g < 8; ++g) AG_STORE(&wbar[512 + g * 32], ep);
            }
        }
        guard = 0;
        while (AG_LOAD(&wbar[512 + gidx * 32]) < ep) {
            __builtin_amdgcn_s_sleep(2);
            if (++guard > (1 << 18)) break;            // fail loud, don't hang
        }
    }
    __syncthreads();
    asm volatile("" ::: "memory");
}

// ---------------------------------------------------------------------------
// One layer, wp-split: block = 64 h-rows x 1 word-pair x 4 segments.
// 512 threads = 8 waves: wave (s = ww&3, rh = ww>>2); lane (h5 = lane&31,
// kh = lane>>5; K split 16/16, combined via shfl_xor(32)).
//  - tab: one 64 KiB plane via global_load_lds dwordx4 (8 rounds).
//  - idx/signs: straight to registers (coalesced 128 B lines per wave).
//  - uint2 gathers feed carry-save counters for both words; bit-sliced
//    compare; OR across segments via fbuf; sc1 plane store.
// ---------------------------------------------------------------------------
__device__ __forceinline__ void layer_phase(
        const uint32_t* __restrict__ prevPlane,  // u32*, 2*H (one wp plane)
        const int* __restrict__ idx,             // (S,H,K)
        const float* __restrict__ signs,         // (S,H,K)
        uint32_t* __restrict__ outPlane,         // u32*, 2*H (one wp plane)
        const int thr, const int hg, const int tid,
        uint2* tab, uint32_t* fbuf) {
    const int lane = tid & 63;
    const int ww   = tid >> 6;
    const int s    = ww & 3;
    const int rh   = ww >> 2;
    const int kh   = lane >> 5;
    const int h5   = lane & 31;
    const int h    = hg * 64 + rh * 32 + h5;

    // ---- issue idx/sign register loads (overlap the GLDS staging) ----
    const size_t gb = ((size_t)s * H + h) * K + kh * 16;
    const int4   i0 = *(const int4*)(idx + gb);
    const int4   i1 = *(const int4*)(idx + gb + 4);
    const int4   i2 = *(const int4*)(idx + gb + 8);
    const int4   i3 = *(const int4*)(idx + gb + 12);
    const float4 s0 = *(const float4*)(signs + gb);
    const float4 s1 = *(const float4*)(signs + gb + 4);
    const float4 s2 = *(const float4*)(signs + gb + 8);
    const float4 s3 = *(const float4*)(signs + gb + 12);

    // ---- stage tab: 64 KiB plane, async direct-to-LDS ----
    {
        uint32_t* lbase = (uint32_t*)tab;
#pragma unroll
        for (int i = 0; i < 8; ++i) {
            const int o = (i * 512 + tid) * 4;      // u32 index, 16 B/lane
            GLDS16(prevPlane + o, lbase + o);
        }
    }
    __syncthreads();   // drains vmcnt (GLDS + reg loads)

    const uint32_t iv[16] = {
        (uint32_t)i0.x, (uint32_t)i0.y, (uint32_t)i0.z, (uint32_t)i0.w,
        (uint32_t)i1.x, (uint32_t)i1.y, (uint32_t)i1.z, (uint32_t)i1.w,
        (uint32_t)i2.x, (uint32_t)i2.y, (uint32_t)i2.z, (uint32_t)i2.w,
        (uint32_t)i3.x, (uint32_t)i3.y, (uint32_t)i3.z, (uint32_t)i3.w };
    const uint32_t pm[16] = {   // ~0 if sign positive
        ~(uint32_t)(__float_as_int(s0.x) >> 31), ~(uint32_t)(__float_as_int(s0.y) >> 31),
        ~(uint32_t)(__float_as_int(s0.z) >> 31), ~(uint32_t)(__float_as_int(s0.w) >> 31),
        ~(uint32_t)(__float_as_int(s1.x) >> 31), ~(uint32_t)(__float_as_int(s1.y) >> 31),
        ~(uint32_t)(__float_as_int(s1.z) >> 31), ~(uint32_t)(__float_as_int(s1.w) >> 31),
        ~(uint32_t)(__float_as_int(s2.x) >> 31), ~(uint32_t)(__float_as_int(s2.y) >> 31),
        ~(uint32_t)(__float_as_int(s2.z) >> 31), ~(uint32_t)(__float_as_int(s2.w) >> 31),
        ~(uint32_t)(__float_as_int(s3.x) >> 31), ~(uint32_t)(__float_as_int(s3.y) >> 31),
        ~(uint32_t)(__float_as_int(s3.z) >> 31), ~(uint32_t)(__float_as_int(s3.w) >> 31) };

    // ---- gather + bit-sliced accumulate (2 words per gather) ----
    uint32_t A0[5] = {0,0,0,0,0}, P0[5] = {0,0,0,0,0};
    uint32_t A1[5] = {0,0,0,0,0}, P1[5] = {0,0,0,0,0};
#pragma unroll
    for (int c8 = 0; c8 < 2; ++c8) {
        uint2 g[8];
#pragma unroll
        for (int j = 0; j < 8; ++j) g[j] = tab[iv[c8 * 8 + j]];
#pragma unroll
        for (int j = 0; j < 8; ++j) {
            const uint32_t pmv = pm[c8 * 8 + j];
            cs5(A0, g[j].x);
            cs5(P0, g[j].x & pmv);
            cs5(A1, g[j].y);
            cs5(P1, g[j].y & pmv);
        }
    }

    // ---- combine k halves (lane^32) -> 6-bit counters ----
    uint32_t A0f[6], P0f[6], A1f[6], P1f[6];
    pair_sum5(A0, A0f);
    pair_sum5(P0, P0f);
    pair_sum5(A1, A1f);
    pair_sum5(P1, P1f);

    const uint32_t f0 = fired_cmp(A0f, P0f, thr);   // word 2wp
    const uint32_t f1 = fired_cmp(A1f, P1f, thr);   // word 2wp+1

    if (kh == 0) {
        fbuf[((s * 2 + rh) * 32 + h5) * 2 + 0] = f0;
        fbuf[((s * 2 + rh) * 32 + h5) * 2 + 1] = f1;
    }
    __syncthreads();

    // ---- OR across 4 segments, write 128 consecutive u32 (sc1) ----
    if (tid < 128) {
        const int rr   = tid >> 6;           // rh
        const int hh   = (tid >> 1) & 31;    // h5
        const int comp = tid & 1;
        uint32_t v = 0;
#pragma unroll
        for (int s2 = 0; s2 < 4; ++s2)
            v |= fbuf[((s2 * 2 + rr) * 32 + hh) * 2 + comp];
        AG_STORE(&outPlane[(size_t)(hg * 64 + rr * 32 + hh) * 2 + comp], v);
    }
}

// ---------------------------------------------------------------------------
// SINGLE fused kernel, NORMAL launch: 256 blocks x 512 threads, 66 KiB LDS
// -> 2 blocks/CU capacity (co-residency robust even at half the device).
// Block = (hg = bid>>1, wp = bid&1); barriers wp-scoped (128 blocks).
// P0 pack+zero(+bar-init by block 0) | bar1 | L1 | bar2 | L2 | bar3 | L3 |
// bar4 | final. Mask prefetch is AFTER bar4 (no cross-phase liveness ->
// no scratch spill; r6's progressive prefetch regressed 50->107 us).
// ---------------------------------------------------------------------------
__global__ __launch_bounds__(512, 4) void fused_kernel(
        const float* __restrict__ x,
        const int* __restrict__ idx0, const float* __restrict__ signs0,
        const int* __restrict__ idxH, const float* __restrict__ signsH,
        const float* __restrict__ wout, const int* __restrict__ thrp,
        uint32_t* __restrict__ xPP,     // [2][F] uint2 planes, as u32*
        uint32_t* __restrict__ actPP, float* __restrict__ out,
        uint32_t* __restrict__ bar) {
    __shared__ uint2    tab[H];                  // 64 KiB (one wp plane)
    __shared__ uint32_t fbuf[4 * 2 * 32 * 2];    // 2 KiB

    const int tid = threadIdx.x;
    const int bid = blockIdx.x;
    const int wp  = bid & 1;
    const int hg  = bid >> 1;                    // 0..127 (64 h-rows each)
    const int gidx = hg & 7;                     // 16 blocks/group/wp
    const int thr = load_threshold(thrp);

    // ---- block 0: zero barrier counters, publish magic (vmcnt-ordered) ----
    if (bid == 0) {
#pragma unroll
        for (int i = 0; i < 4; ++i) AG_STORE(&bar[i * 512 + tid], 0u);
        asm volatile("s_waitcnt vmcnt(0)" ::: "memory");
        __syncthreads();
        if (tid == 0) {
            AG_STORE(&bar[MAG_IDX], MAGIC_A);
            AG_STORE(&bar[MAG_IDX + 1], MAGIC_B);
        }
    }

    // ---- P0: zero out (sc1) + pack x -> xPP (sc1) ----
    {
        const int zi = bid * 512 + tid;
        if (zi < B * C) AG_STORE((uint32_t*)&out[zi], 0u);

        const int b   = tid & 127;
        const int wv  = (tid >> 6) & 1;       // word pair of this wave
        const int sub = tid >> 7;             // 0..3 -> j = 2*sub..2*sub+1
        const int f0  = bid * 32;
        const float4* xr = (const float4*)(x + (size_t)b * F + f0);
#pragma unroll
        for (int jj = 0; jj < 2; ++jj) {
            const int j = sub * 2 + jj;
            const float4 v = xr[j];
            const uint64_t m0 = __ballot(v.x > 0.5f);
            const uint64_t m1 = __ballot(v.y > 0.5f);
            const uint64_t m2 = __ballot(v.z > 0.5f);
            const uint64_t m3 = __ballot(v.w > 0.5f);
            if ((tid & 63) == 0) {
                const int f = f0 + 4 * j;
                unsigned long long* q =
                    (unsigned long long*)(xPP + ((size_t)wv * F + f) * 2);
                AG_STORE(q + 0, (unsigned long long)m0);
                AG_STORE(q + 1, (unsigned long long)m1);
                AG_STORE(q + 2, (unsigned long long)m2);
                AG_STORE(q + 3, (unsigned long long)m3);
            }
        }
    }
    wp_barrier(bar, wp, 1, tid, gidx, true);

    const uint32_t* xPlane = xPP + (size_t)wp * 2 * F;
    uint32_t* pl0 = actPP + (size_t)(0 * 2 + wp) * 2 * H;
    uint32_t* pl1 = actPP + (size_t)(1 * 2 + wp) * 2 * H;
    uint32_t* pl2 = actPP + (size_t)(2 * 2 + wp) * 2 * H;
    const int*   idx2   = idxH;
    const float* signs2 = signsH;
    const int*   idx3   = idxH + (size_t)S * H * K;
    const float* signs3 = signsH + (size_t)S * H * K;

    layer_phase(xPlane, idx0, signs0, pl0, thr, hg, tid, tab, fbuf);
    wp_barrier(bar, wp, 2, tid, gidx, false);

    layer_phase(pl0, idx2, signs2, pl1, thr, hg, tid, tab, fbuf);
    wp_barrier(bar, wp, 3, tid, gidx, false);

    layer_phase(pl1, idx3, signs3, pl2, thr, hg, tid, tab, fbuf);
    wp_barrier(bar, wp, 4, tid, gidx, false);

    // ---- final: wave = (b, hc); all mask words prefetched upfront, then
    // batch-of-4 bit-walk with NAMED SCALARS only (no arrays -> no scratch).
    {
        const int lane = tid & 63;
        const int gw   = bid * 8 + (tid >> 6);
        const int fb   = gw >> 4;                    // batch b
        const int hc   = gw & 15;                    // h-chunk (512 h)
        const int w32  = fb >> 5;
        const int fwp  = w32 >> 1;
        const int comp = w32 & 1;
        const int bit  = fb & 31;

        uint32_t mv[L][8];
#pragma unroll
        for (int l = 0; l < L; ++l) {
            const uint32_t* aT = actPP + (size_t)(l * 2 + fwp) * 2 * H + comp;
#pragma unroll
            for (int r = 0; r < 8; ++r)
                mv[l][r] = AG_LOAD(&aT[(size_t)(hc * 512 + r * 64 + lane) * 2]);
        }

        float acc0 = 0.0f, acc1 = 0.0f;
        const int c1 = 64 + lane;
        const bool c1v = (c1 < C);

#pragma unroll
        for (int l = 0; l < L; ++l) {
            const float* wl = wout + (size_t)l * H * C;
#pragma unroll
            for (int r = 0; r < 8; ++r) {
                const int hbase = hc * 512 + r * 64;
                uint64_t hm = __ballot((mv[l][r] >> bit) & 1u);
                while (hm) {
                    // __ffsll(0)-1 == -1, and hm &= hm-1 is a no-op at 0:
                    // slot extraction needs no conditionals.
                    const int sa = __ffsll((unsigned long long)hm) - 1; hm &= hm - 1;
                    const int sb = __ffsll((unsigned long long)hm) - 1; hm &= hm - 1;
                    const int sc = __ffsll((unsigned long long)hm) - 1; hm &= hm - 1;
                    const int sd = __ffsll((unsigned long long)hm) - 1; hm &= hm - 1;
                    float a0, a1 = 0.0f, b0 = 0.0f, b1 = 0.0f;
                    float c0 = 0.0f, c1f = 0.0f, d0 = 0.0f, d1 = 0.0f;
                    {   // sa is always valid inside the while
                        const float* w = wl + (size_t)(hbase + sa) * C;
                        a0 = w[lane];
                        if (c1v) a1 = w[c1];
                    }
                    if (sb >= 0) {
                        const float* w = wl + (size_t)(hbase + sb) * C;
                        b0 = w[lane];
                        if (c1v) b1 = w[c1];
                    }
                    if (sc >= 0) {
                        const float* w = wl + (size_t)(hbase + sc) * C;
                        c0 = w[lane];
                        if (c1v) c1f = w[c1];
                    }
                    if (sd >= 0) {
                        const float* w = wl + (size_t)(hbase + sd) * C;
                        d0 = w[lane];
                        if (c1v) d1 = w[c1];
                    }
                    acc0 += (a0 + b0) + (c0 + d0);
                    acc1 += (a1 + b1) + (c1f + d1);
                }
            }
        }
        atomicAdd(&out[fb * C + lane], acc0);
        if (c1v) atomicAdd(&out[fb * C + c1], acc1);
    }
}

// ---------------------------------------------------------------------------
extern "C" void kernel_launch(void* const* d_in, const int* in_sizes, int n_in,
                              void* d_out, int out_size, void* d_ws, size_t ws_size,
                              hipStream_t stream) {
    const float* x      = (const float*)d_in[0];   // (B,F)
    const float* signs0 = (const float*)d_in[1];   // (S,H,K)
    const float* signsH = (const float*)d_in[2];   // (L-1,S,H,K)
    const float* wout   = (const float*)d_in[3];   // (L,H,C)
    const int*   idx0   = (const int*)d_in[4];     // (S,H,K)
    const int*   idxH   = (const int*)d_in[5];     // (L-1,S,H,K)
    const int*   thr    = (const int*)d_in[6];     // scalar
    float* out = (float*)d_out;                    // (B,C)

    // Workspace: xPP [2][F] uint2 (128 KiB), actPP [L][2][H] uint2 (384 KiB),
    // barrier state (2 wp x 1024 u32 + magic line)
    uint32_t* xPP   = (uint32_t*)d_ws;
    uint32_t* actPP = xPP + (size_t)4 * F;
    uint32_t* bar   = actPP + (size_t)12 * H;

    fused_kernel<<<NBLK, NTHR, 0, stream>>>(x, idx0, signs0, idxH, signsH,
                                            wout, thr, xPP, actPP, out, bar);
}